// Round 4
// baseline (464.423 us; speedup 1.0000x reference)
//
#include <hip/hip_runtime.h>
#include <hip/hip_bf16.h>

// Problem constants (from reference)
#define M_TOTAL 65536   // N_IDS
#define ND      128     // N_DOCS
#define FDIM    220     // FEATURE_DIM
#define KPAD    224     // FDIM padded to multiple of 32 for MFMA
#define HID     768     // HIDDEN
#define G8      28      // groups of 8 cols per 224-col padded row

using bf16_t = __hip_bfloat16;
using bf16x8 = __attribute__((ext_vector_type(8))) short;  // 8 bf16 = 4 VGPRs
using f32x4  = __attribute__((ext_vector_type(4))) float;  // native vec4 (MFMA acc + IO)

struct __align__(16) bf16v8 { bf16_t v[8]; };

__device__ __forceinline__ float slog(float x) {
  return copysignf(log1pf(fabsf(x)), x);  // log(|x|+1) * sign(x)
}

__device__ __forceinline__ f32x4 slog4(f32x4 f) {
  f32x4 y;
  y[0] = slog(f[0]); y[1] = slog(f[1]); y[2] = slog(f[2]); y[3] = slog(f[3]);
  return y;
}

__device__ __forceinline__ bf16x8 pack8(f32x4 a, f32x4 b) {
  bf16v8 h;
  h.v[0] = __float2bfloat16(a[0]); h.v[1] = __float2bfloat16(a[1]);
  h.v[2] = __float2bfloat16(a[2]); h.v[3] = __float2bfloat16(a[3]);
  h.v[4] = __float2bfloat16(b[0]); h.v[5] = __float2bfloat16(b[1]);
  h.v[6] = __float2bfloat16(b[2]); h.v[7] = __float2bfloat16(b[3]);
  return __builtin_bit_cast(bf16x8, h);
}

// ---------------------------------------------------------------------------
// Kernel 1 (tiny): W [768x220] fp32 -> Wb [768x224] bf16 in d_ws. 84 blocks.
// ---------------------------------------------------------------------------
__global__ __launch_bounds__(256) void convert_w_kernel(
    const float* __restrict__ W, bf16_t* __restrict__ Wb)
{
  const int j   = blockIdx.x * 256 + threadIdx.x;  // exact: 768*28 = 84*256
  const int row = j / G8;
  const int g   = j % G8;

  const float* src = W + (size_t)row * FDIM + g * 8;
  const f32x4 f0 = *(const f32x4*)src;            // cols 216..219 ok for g=27
  f32x4 f1;
  if (g < 27) f1 = *(const f32x4*)(src + 4);
  else        { f1[0] = 0.f; f1[1] = 0.f; f1[2] = 0.f; f1[3] = 0.f; }  // pad 220..223
  *(bf16v8*)(Wb + (size_t)row * KPAD + g * 8) = __builtin_bit_cast(bf16v8, pack8(f0, f1));
}

// ---------------------------------------------------------------------------
// Kernel 2 (fused, barrier-free, high-occupancy): each wave owns 16 rows
//   (the MFMA M=16 floor). 1024 blocks x 4 waves = 4096 waves = 16 waves/CU
//   (4 waves/SIMD) — 2x Round-2's occupancy, to cover gather (L3/HBM) and
//   B-load (L2) latency. Gather lands DIRECTLY in the A fragment: lane
//   (q,l15) holds A row l15, cols kb*32+q*8..+7 — one f32x4-pair per kb,
//   and per instruction the 4 q-lanes of a row form one contiguous 128 B
//   line. slog in fp32, fb written once, pack bf16 -> af[7].
//   GEMM: 6 x 128-col N-tiles, acc[8], B from L2-resident Wb (344 KB).
//   No LDS, no barriers, plain stores (nt caused +59 MB RMW inflation in R2).
// ---------------------------------------------------------------------------
__global__ __launch_bounds__(256, 4) void fused_gather_gemm_kernel(
    const int2* __restrict__ ids, const float* __restrict__ table,
    const bf16_t* __restrict__ Wb, const float* __restrict__ bias,
    float* __restrict__ out, float* __restrict__ fb)
{
  const int tid  = threadIdx.x;
  const int bm   = blockIdx.x;       // 0..1023
  const int wave = tid >> 6;         // 0..3  -> owns rows wave*16..+15
  const int lane = tid & 63;
  const int l15  = lane & 15;
  const int q    = lane >> 4;

  const int rbase = bm * 64 + wave * 16;
  const int grow  = rbase + l15;     // this lane's gathered row

  const int2 p = ids[grow];
  const float* srow = table + ((size_t)p.x * ND + p.y) * FDIM;
  float*       frow = fb + (size_t)grow * FDIM;

  // ---- gather + slog + fb-write + pack, straight into A fragments ----
  bf16x8 af[7];
#pragma unroll
  for (int kb = 0; kb < 7; ++kb) {
    const int  c0   = kb * 32 + q * 8;
    const bool tail = (kb == 6) && (q == 3);   // cols 216..223: only 4 real
    f32x4 lo = *(const f32x4*)(srow + c0);
    f32x4 hi;
    if (!tail) hi = *(const f32x4*)(srow + c0 + 4);
    else       { hi[0] = 0.f; hi[1] = 0.f; hi[2] = 0.f; hi[3] = 0.f; }
    lo = slog4(lo);
    if (!tail) hi = slog4(hi);                  // pad stays 0
    *(f32x4*)(frow + c0) = lo;
    if (!tail) *(f32x4*)(frow + c0 + 4) = hi;
    af[kb] = pack8(lo, hi);
  }
  // no barrier: fragments are wave-private registers

  // ---- GEMM: 6 N-tiles of 128 cols; B rows bn*128 + ni*16 + l15 ----
  for (int bn = 0; bn < 6; ++bn) {
    f32x4 acc[8];
#pragma unroll
    for (int j = 0; j < 8; ++j) acc[j] = (f32x4){0.f, 0.f, 0.f, 0.f};

    const bf16_t* Wbase = Wb + (size_t)(bn * 128 + l15) * KPAD + q * 8;

#pragma unroll
    for (int kb = 0; kb < 7; ++kb) {
      bf16x8 bg[8];
#pragma unroll
      for (int ni = 0; ni < 8; ++ni)
        bg[ni] = *(const bf16x8*)(Wbase + (size_t)ni * 16 * KPAD + kb * 32);
#pragma unroll
      for (int ni = 0; ni < 8; ++ni)
        acc[ni] = __builtin_amdgcn_mfma_f32_16x16x32_bf16(
            af[kb], bg[ni], acc[ni], 0, 0, 0);
    }

    // epilogue: C/D layout col = lane&15, row = (lane>>4)*4 + reg [m89-verified]
    const int col0 = bn * 128 + l15;
    const int row0 = rbase + q * 4;

    float bv[8];
#pragma unroll
    for (int ni = 0; ni < 8; ++ni) bv[ni] = bias[col0 + ni * 16];

#pragma unroll
    for (int r = 0; r < 4; ++r) {
      const size_t rowoff = (size_t)(row0 + r) * HID;
#pragma unroll
      for (int ni = 0; ni < 8; ++ni) {   // ni innermost: adjacent 64B halves
        float v = acc[ni][r] + bv[ni];
        out[rowoff + col0 + ni * 16] = v > 0.f ? v : 0.f;
      }
    }
  }
}

extern "C" void kernel_launch(void* const* d_in, const int* in_sizes, int n_in,
                              void* d_out, int out_size, void* d_ws, size_t ws_size,
                              hipStream_t stream) {
  (void)in_sizes; (void)n_in; (void)out_size; (void)ws_size;

  const int2*  ids   = (const int2*)d_in[0];
  const float* table = (const float*)d_in[1];
  const float* W     = (const float*)d_in[2];
  const float* bias  = (const float*)d_in[3];

  float* out_embeds = (float*)d_out;                          // 65536*768 fp32
  float* fb_f32     = (float*)d_out + (size_t)M_TOTAL * HID;  // 65536*220 fp32

  bf16_t* Wb = (bf16_t*)d_ws;  // 768*224 bf16 = 344 KB

  convert_w_kernel<<<(HID * G8) / 256, 256, 0, stream>>>(W, Wb);

  fused_gather_gemm_kernel<<<M_TOTAL / 64, 256, 0, stream>>>(
      ids, table, Wb, bias, out_embeds, fb_f32);
}